// Round 18
// baseline (54038.422 us; speedup 1.0000x reference)
//
#include <hip/hip_runtime.h>
#include <hip/hip_bf16.h>
#include <stdint.h>

// ============================================================================
// 2-layer GRU — ROUND 18: 2-phase global schedule + L2-CACHED state reads.
//   B=64, S=1024, I=256, H=1024, O=256, L=2
// R8-R17 invariant = sc1 byte volume (~40MB/step, every WG re-reads full
// state, L2 bypassed). R12 PROVED plain-reads + agent-acquire-fence are
// CORRECT on gfx950; it was slow only because staggered dataflow releases
// scattered fences -> L2 thrash. Fix: 2 simultaneous-release global phases
// per step so all ~25 WGs/XCD fence together, then share L2 line fills.
//   Phase A(tt): zr0(tt) [tt<Sc]; zr1(tt-1) [1<=tt<=Sc]; y(tt-2) [tt>=2]
//   Phase B(tt): g0(tt) [tt<Sc]; g1(tt-1) [1<=tt<=Sc]; hs [tt==Sc+1]
// tt = 0..Sc+1. Barrier: 200 padded sc1 stamps -> wg0 sweeps -> epoch store
// -> all poll epoch -> acquire fence (buffer_inv). ALL writes sc1 (L2 never
// dirty -> inv can't discard); reads plain (L1/L2 cached, fresh post-fence).
// Buffers: h0[2], h1[2] (slot t&1 holds h(t)); z0,rh0,z1,rh1 single
// (write-A, read-B, rewrite next A: barrier-separated). h(-1) in slot 1.
// ============================================================================

#define NWG 200
#define TPB 256

typedef unsigned long long u64;
typedef __attribute__((ext_vector_type(8))) short bfrag;
typedef __attribute__((ext_vector_type(4))) float f32x4;

constexpr int Bc = 64, Sc = 1024, Ic = 256, Hc = 1024, Oc = 256;

struct Args {
  const float *x, *h0in;
  const float *W1[7], *W2[7], *bias[7];
  unsigned short *h0[2], *h1[2], *z0, *rh0, *z1, *rh1;
  unsigned *sl;       // 200 stamp slots (128B apart) + epoch at [200*32]
  float *y, *hs;
};

__device__ __forceinline__ unsigned ald32(const void *p) {
  return __hip_atomic_load((const unsigned *)p, __ATOMIC_RELAXED, __HIP_MEMORY_SCOPE_AGENT);
}
__device__ __forceinline__ void ast32(void *p, unsigned v) {
  __hip_atomic_store((unsigned *)p, v, __ATOMIC_RELAXED, __HIP_MEMORY_SCOPE_AGENT);
}
__device__ __forceinline__ unsigned short f2b(float x) {
  __hip_bfloat16 b = __float2bfloat16(x);
  return __builtin_bit_cast(unsigned short, b);
}
__device__ __forceinline__ float b2f(unsigned short u) {
  return __uint_as_float(((unsigned)u) << 16);
}
__device__ __forceinline__ size_t tidx32(int row, int col) {
  return ((size_t)(col >> 3) * 64 + row) * 4 + ((col & 7) >> 1);
}

// ---------------- global 2-phase barrier -------------------------------------
// arrive: sc1 stamp to own padded slot (after syncthreads vmcnt-drain).
// wg0: all-thread sweep of 200 slots; on success sc1-store epoch=n.
// all: thread0 polls epoch >= n; syncthreads; ACQUIRE fence (buffer_inv) ->
// subsequent PLAIN loads see fresh data and share L2 fills across the XCD.
__device__ void gbar2(unsigned *sl, int wg, unsigned n) {
  __shared__ int notdone;
  const int tid = threadIdx.x;
  unsigned *ep = sl + (size_t)NWG * 32;
  __syncthreads();                      // drain: prior sc1 stores ACKed at LLC
  if (tid == 0)
    ast32(sl + (size_t)wg * 32, n);
  if (wg == 0) {
    float d = 1.0f;
    while (true) {
      int bad = 0;
      if (tid < NWG)
        bad = (ald32(sl + (size_t)tid * 32) < n);
      if (tid == 0) notdone = 0;
      __syncthreads();
      if (bad) notdone = 1;
      __syncthreads();
      if (!notdone) break;
#pragma unroll
      for (int i = 0; i < 16; ++i) d = fmaf(d, 1.0000001f, 1e-30f);
      asm volatile("" :: "v"(d));
    }
    if (tid == 0) ast32(ep, n);
  } else {
    if (tid == 0) {
      float d = 1.0f;
      while (ald32(ep) < n) {
#pragma unroll
        for (int i = 0; i < 16; ++i) d = fmaf(d, 1.0000001f, 1e-30f);
        asm volatile("" :: "v"(d));
      }
    }
  }
  __syncthreads();
  __builtin_amdgcn_fence(__ATOMIC_ACQUIRE, "agent");   // inv L1/L2 (R12-proven)
}

// ---------------- MFMA segments (PLAIN cached loads, tiled layout) ----------
__device__ void seg_h(f32x4 *acc, const unsigned short *hb, const short *wl,
                      int nkoff, int lane, int rbase) {
  const bfrag *tp = (const bfrag *)hb + ((lane >> 4) * 64 + rbase + (lane & 15));
#pragma unroll
  for (int ks = 0; ks < 32; ++ks) {
    bfrag av = tp[(size_t)ks * 256];
    const short *wp = wl + (((size_t)(nkoff + ks) * 2) * 64 + lane) * 8;
    acc[0] = __builtin_amdgcn_mfma_f32_16x16x32_bf16(av, *(const bfrag *)wp, acc[0], 0, 0, 0);
    acc[1] = __builtin_amdgcn_mfma_f32_16x16x32_bf16(av, *(const bfrag *)(wp + 512), acc[1], 0, 0, 0);
  }
}
__device__ void seg_x(f32x4 *acc, const float *xt, const short *wl, int lane, int rbase) {
  const float4 *xp = (const float4 *)(xt + (size_t)(rbase + (lane & 15)) * Sc * Ic) + (lane >> 4) * 2;
  float4 xv[16];
#pragma unroll
  for (int q = 0; q < 8; ++q) {
    xv[2 * q]     = xp[(size_t)q * 8];
    xv[2 * q + 1] = xp[(size_t)q * 8 + 1];
  }
#pragma unroll
  for (int q = 0; q < 8; ++q) {
    bfrag av;
    const float *f0 = (const float *)&xv[2 * q];
    const float *f1 = (const float *)&xv[2 * q + 1];
#pragma unroll
    for (int e = 0; e < 4; ++e) {
      av[e]     = (short)f2b(f0[e]);
      av[4 + e] = (short)f2b(f1[e]);
    }
    const short *wp = wl + (((size_t)q * 2) * 64 + lane) * 8;
    acc[0] = __builtin_amdgcn_mfma_f32_16x16x32_bf16(av, *(const bfrag *)wp, acc[0], 0, 0, 0);
    acc[1] = __builtin_amdgcn_mfma_f32_16x16x32_bf16(av, *(const bfrag *)(wp + 512), acc[1], 0, 0, 0);
  }
}

// ---------------- epilogues (plain reads, sc1 writes) ------------------------
__device__ void store_sig(unsigned short *out, f32x4 *acc, int c0, int lane, int rbase) {
#pragma unroll
  for (int nt = 0; nt < 2; ++nt) {
    int col = c0 + nt * 16 + (lane & 15);
#pragma unroll
    for (int j = 0; j < 4; ++j) {
      float v = 1.f / (1.f + expf(-acc[nt][j]));
      float vo = __shfl_xor(v, 1);
      if (!(lane & 1)) {
        int row = rbase + (lane >> 4) * 4 + j;
        ast32((unsigned *)out + tidx32(row, col),
              (unsigned)f2b(v) | ((unsigned)f2b(vo) << 16));
      }
    }
  }
}
__device__ void store_rh(unsigned short *out, const unsigned short *hb, f32x4 *acc,
                         int c0, int lane, int rbase) {
  unsigned hw[8];
#pragma unroll
  for (int nt = 0; nt < 2; ++nt)
#pragma unroll
    for (int j = 0; j < 4; ++j) {
      int col = c0 + nt * 16 + (lane & 15);
      int row = rbase + (lane >> 4) * 4 + j;
      hw[nt * 4 + j] = *((const unsigned *)hb + tidx32(row, col));
    }
#pragma unroll
  for (int nt = 0; nt < 2; ++nt) {
    int col = c0 + nt * 16 + (lane & 15);
#pragma unroll
    for (int j = 0; j < 4; ++j) {
      float v = 1.f / (1.f + expf(-acc[nt][j]));
      float vo = __shfl_xor(v, 1);
      if (!(lane & 1)) {
        unsigned w = hw[nt * 4 + j];
        int row = rbase + (lane >> 4) * 4 + j;
        unsigned pk = (unsigned)f2b(v * b2f((unsigned short)(w & 0xffff)))
                    | ((unsigned)f2b(vo * b2f((unsigned short)(w >> 16))) << 16);
        ast32((unsigned *)out + tidx32(row, col), pk);
      }
    }
  }
}
__device__ void store_gupd(unsigned short *hnew, const unsigned short *hold,
                           const unsigned short *zb, f32x4 *acc, int c0, int lane, int rbase) {
  unsigned zw[8], hw[8];
#pragma unroll
  for (int nt = 0; nt < 2; ++nt)
#pragma unroll
    for (int j = 0; j < 4; ++j) {
      int col = c0 + nt * 16 + (lane & 15);
      size_t iw = tidx32(rbase + (lane >> 4) * 4 + j, col);
      zw[nt * 4 + j] = *((const unsigned *)zb + iw);
      hw[nt * 4 + j] = *((const unsigned *)hold + iw);
    }
#pragma unroll
  for (int nt = 0; nt < 2; ++nt) {
    int col = c0 + nt * 16 + (lane & 15);
#pragma unroll
    for (int j = 0; j < 4; ++j) {
      float g = tanhf(acc[nt][j]);
      float go = __shfl_xor(g, 1);
      if (!(lane & 1)) {
        unsigned wz = zw[nt * 4 + j], wh = hw[nt * 4 + j];
        float zl = b2f((unsigned short)(wz & 0xffff)), zh = b2f((unsigned short)(wz >> 16));
        float hl = b2f((unsigned short)(wh & 0xffff)), hh = b2f((unsigned short)(wh >> 16));
        float hn0 = zl * hl + (1.f - zl) * g;
        float hn1 = zh * hh + (1.f - zh) * go;
        ast32((unsigned *)hnew + tidx32(rbase + (lane >> 4) * 4 + j, col),
              (unsigned)f2b(hn0) | ((unsigned)f2b(hn1) << 16));
      }
    }
  }
}

// ---------------- weight packing (unchanged) ---------------------------------
__device__ void pack_weights(short *wl, const float *W1, int K1, int ld1,
                             const float *W2, int K2, int ld2, int c0) {
  int NK = (K1 + K2) / 32;
  for (int slot = threadIdx.x; slot < NK * 128; slot += TPB) {
    int ks = slot >> 7, rem = slot & 127, nt = rem >> 6, ln = rem & 63;
    int c = c0 + nt * 16 + (ln & 15);
    int k0 = ks * 32 + (ln >> 4) * 8;
    short *dst = wl + (((size_t)ks * 2 + nt) * 64 + ln) * 8;
#pragma unroll
    for (int j = 0; j < 8; ++j) {
      int k = k0 + j;
      float w = (k < K1) ? W1[(size_t)k * ld1 + c] : W2[(size_t)(k - K1) * ld2 + c];
      dst[j] = (short)f2b(w);
    }
  }
}

// ---------------- main --------------------------------------------------------
__global__ void __launch_bounds__(TPB) gru_ph(Args a) {
  extern __shared__ short wl[];
  const int wg = blockIdx.x, tid = threadIdx.x;
  const int lane = tid & 63, wid = tid >> 6, rbase = wid * 16;
  const int gate = (wg < 32) ? 0 : (wg < 64) ? 1 : (wg < 96) ? 2 :
                   (wg < 128) ? 3 : (wg < 160) ? 4 : (wg < 192) ? 5 : 6;
  const int c0 = (gate == 6) ? (wg - 192) * 32 : (wg - gate * 32) * 32;
  static const int K1tab[7] = {256, 256, 256, 1024, 1024, 1024, 1024};
  static const int K2tab[7] = {1024, 1024, 1024, 1024, 1024, 1024, 0};
  const int ld1 = (gate == 6) ? Oc : Hc;

  pack_weights(wl, a.W1[gate], K1tab[gate], ld1, a.W2[gate], K2tab[gate], Hc, c0);

  // init h(-1) into slot 1, TILED layout, sc1 stores
  for (int u = wg * TPB + tid; u < Bc * Hc / 2; u += NWG * TPB) {
    int tile = u >> 2, word = u & 3;
    int b = tile & 63, oct = tile >> 6;
    int c = oct * 8 + word * 2;
    const float *s0 = a.h0in + (size_t)(b * 2) * Hc + c;
    const float *s1 = a.h0in + (size_t)(b * 2 + 1) * Hc + c;
    ast32((unsigned *)a.h0[1] + u, (unsigned)f2b(s0[0]) | ((unsigned)f2b(s0[1]) << 16));
    ast32((unsigned *)a.h1[1] + u, (unsigned)f2b(s1[0]) | ((unsigned)f2b(s1[1]) << 16));
  }
  unsigned bn = 0;
  gbar2(a.sl, wg, ++bn);

  const float *bias = a.bias[gate];

  for (int tt = 0; tt <= Sc + 1; ++tt) {
    // ---------------- Phase A: zr0(tt), zr1(tt-1), y(tt-2) ----------------
    if (gate <= 1) {
      if (tt < Sc) {
        const unsigned short *h0c = a.h0[(tt + 1) & 1];          // h0(tt-1)
        float b0 = bias[c0 + (lane & 15)], b1 = bias[c0 + 16 + (lane & 15)];
        f32x4 acc[2] = {{b0, b0, b0, b0}, {b1, b1, b1, b1}};
        seg_x(acc, a.x + (size_t)tt * Ic, wl, lane, rbase);
        seg_h(acc, h0c, wl, 8, lane, rbase);
        if (gate == 0) store_sig(a.z0, acc, c0, lane, rbase);
        else           store_rh(a.rh0, h0c, acc, c0, lane, rbase);
      }
    } else if (gate == 3 || gate == 4) {
      if (tt >= 1 && tt <= Sc) {
        int s = tt - 1;
        const unsigned short *h0n = a.h0[s & 1];                 // h0(s)
        const unsigned short *h1c = a.h1[(s + 1) & 1];           // h1(s-1)
        float b0 = bias[c0 + (lane & 15)], b1 = bias[c0 + 16 + (lane & 15)];
        f32x4 acc[2] = {{b0, b0, b0, b0}, {b1, b1, b1, b1}};
        seg_h(acc, h0n, wl, 0, lane, rbase);
        seg_h(acc, h1c, wl, 32, lane, rbase);
        if (gate == 3) store_sig(a.z1, acc, c0, lane, rbase);
        else           store_rh(a.rh1, h1c, acc, c0, lane, rbase);
      }
    } else if (gate == 6) {
      if (tt >= 2) {
        int s = tt - 2;
        const unsigned short *h1t = a.h1[s & 1];                 // h1(s)
        float b0 = bias[c0 + (lane & 15)], b1 = bias[c0 + 16 + (lane & 15)];
        f32x4 acc[2] = {{b0, b0, b0, b0}, {b1, b1, b1, b1}};
        seg_h(acc, h1t, wl, 0, lane, rbase);
#pragma unroll
        for (int nt = 0; nt < 2; ++nt) {
          int col = c0 + nt * 16 + (lane & 15);
#pragma unroll
          for (int j = 0; j < 4; ++j) {
            int row = rbase + (lane >> 4) * 4 + j;
            ast32((unsigned *)(a.y + ((size_t)row * Sc + s) * Oc + col),
                  __float_as_uint(acc[nt][j]));
          }
        }
      }
    }
    gbar2(a.sl, wg, ++bn);

    // ---------------- Phase B: g0(tt), g1(tt-1), hs@end -------------------
    if (gate == 2) {
      if (tt < Sc) {
        const unsigned short *h0c = a.h0[(tt + 1) & 1];          // h0(tt-1)
        unsigned short *h0n = a.h0[tt & 1];                      // h0(tt)
        float b0 = bias[c0 + (lane & 15)], b1 = bias[c0 + 16 + (lane & 15)];
        f32x4 acc[2] = {{b0, b0, b0, b0}, {b1, b1, b1, b1}};
        seg_x(acc, a.x + (size_t)tt * Ic, wl, lane, rbase);
        seg_h(acc, a.rh0, wl, 8, lane, rbase);
        store_gupd(h0n, h0c, a.z0, acc, c0, lane, rbase);
      } else if (tt == Sc + 1) {
        // hs: final h0(Sc-1)=h0[1], h1(Sc-1)=h1[1]  (Sc-1 odd)
        for (int k = (wg - 64) * TPB + tid; k < Bc * 2 * Hc; k += 32 * TPB) {
          int b = k >> 11, l = (k >> 10) & 1, h = k & 1023;
          const unsigned short *src = l ? a.h1[1] : a.h0[1];
          size_t i16 = ((size_t)(h >> 3) * 64 + b) * 8 + (h & 7);
          unsigned wv = *((const unsigned *)src + (i16 >> 1));
          float v = b2f((unsigned short)((h & 1) ? (wv >> 16) : (wv & 0xffff)));
          ast32((unsigned *)(a.hs + k), __float_as_uint(v));
        }
      }
    } else if (gate == 5) {
      if (tt >= 1 && tt <= Sc) {
        int s = tt - 1;
        const unsigned short *h0s = a.h0[s & 1];                 // h0(s)
        const unsigned short *h1c = a.h1[(s + 1) & 1];           // h1(s-1)
        unsigned short *h1n = a.h1[s & 1];                       // h1(s)
        float b0 = bias[c0 + (lane & 15)], b1 = bias[c0 + 16 + (lane & 15)];
        f32x4 acc[2] = {{b0, b0, b0, b0}, {b1, b1, b1, b1}};
        seg_h(acc, h0s, wl, 0, lane, rbase);
        seg_h(acc, a.rh1, wl, 32, lane, rbase);
        store_gupd(h1n, h1c, a.z1, acc, c0, lane, rbase);
      }
    }
    gbar2(a.sl, wg, ++bn);
  }
}

extern "C" void kernel_launch(void *const *d_in, const int *in_sizes, int n_in,
                              void *d_out, int out_size, void *d_ws, size_t ws_size,
                              hipStream_t stream) {
  (void)in_sizes; (void)n_in; (void)out_size; (void)ws_size;
  Args a;
  a.x    = (const float *)d_in[0];
  a.h0in = (const float *)d_in[1];
  a.W1[0] = (const float *)d_in[2];  a.W2[0] = (const float *)d_in[5];  a.bias[0] = (const float *)d_in[6];
  a.W1[1] = (const float *)d_in[3];  a.W2[1] = (const float *)d_in[7];  a.bias[1] = (const float *)d_in[8];
  a.W1[2] = (const float *)d_in[4];  a.W2[2] = (const float *)d_in[9];  a.bias[2] = (const float *)d_in[10];
  a.W1[3] = (const float *)d_in[11]; a.W2[3] = (const float *)d_in[14]; a.bias[3] = (const float *)d_in[15];
  a.W1[4] = (const float *)d_in[12]; a.W2[4] = (const float *)d_in[16]; a.bias[4] = (const float *)d_in[17];
  a.W1[5] = (const float *)d_in[13]; a.W2[5] = (const float *)d_in[18]; a.bias[5] = (const float *)d_in[19];
  a.W1[6] = (const float *)d_in[20]; a.W2[6] = nullptr;                 a.bias[6] = (const float *)d_in[21];

  char *w = (char *)d_ws;
  a.h0[0] = (unsigned short *)(w + 0);
  a.h0[1] = (unsigned short *)(w + 131072);
  a.h1[0] = (unsigned short *)(w + 262144);
  a.h1[1] = (unsigned short *)(w + 393216);
  a.z0    = (unsigned short *)(w + 524288);
  a.rh0   = (unsigned short *)(w + 655360);
  a.z1    = (unsigned short *)(w + 786432);
  a.rh1   = (unsigned short *)(w + 917504);
  a.sl    = (unsigned *)(w + 1048576);
  a.y   = (float *)d_out;
  a.hs  = a.y + (size_t)Bc * Sc * Oc;

  (void)hipMemsetAsync(a.sl, 0, 32768, stream);
  (void)hipFuncSetAttribute((const void *)gru_ph,
                            hipFuncAttributeMaxDynamicSharedMemorySize, 131072);
  gru_ph<<<NWG, TPB, 131072, stream>>>(a);
}